// Round 1
// baseline (4386.448 us; speedup 1.0000x reference)
//
#include <hip/hip_runtime.h>

#define NNODES 100000
#define NEDGES 1600000
#define IND 128
#define HIDD 128
#define OUTD 64

// ---------- degree / normalization ----------
__global__ void init_deg(float* deg, int n) {
    int i = blockIdx.x * blockDim.x + threadIdx.x;
    if (i < n) deg[i] = 1.0f;   // self-loop
}

__global__ void count_deg(const int* __restrict__ dst, float* deg, int e) {
    int i = blockIdx.x * blockDim.x + threadIdx.x;
    if (i < e) atomicAdd(&deg[dst[i]], 1.0f);
}

__global__ void finalize_dinv(float* deg, int n) {
    int i = blockIdx.x * blockDim.x + threadIdx.x;
    if (i < n) deg[i] = rsqrtf(deg[i]);
}

// ---------- dense GEMM: C[n x M] = A[n x K] * W[K x M], row-major ----------
// 256 threads/block, 32 rows/block. A tile staged in LDS; W streamed from L2.
template<int K, int M>
__global__ void gemm_kernel(const float* __restrict__ A, const float* __restrict__ W,
                            float* __restrict__ C, int n) {
    __shared__ float As[32 * K];
    const int row0 = blockIdx.x * 32;

    // cooperative A-tile load (coalesced)
    for (int idx = threadIdx.x; idx < 32 * K; idx += 256) {
        int r = idx / K, k = idx % K;
        int gr = row0 + r;
        As[idx] = (gr < n) ? A[(size_t)gr * K + k] : 0.0f;
    }
    __syncthreads();

    constexpr int NGRP = 256 / M;        // groups of threads along rows
    constexpr int RPT  = 32 / NGRP;      // rows per thread
    const int col  = threadIdx.x % M;
    const int rgrp = threadIdx.x / M;

    float acc[RPT];
#pragma unroll
    for (int i = 0; i < RPT; i++) acc[i] = 0.0f;

    for (int k = 0; k < K; k++) {
        float b = W[k * M + col];        // coalesced across threads, L1/L2-hot
#pragma unroll
        for (int i = 0; i < RPT; i++) {
            acc[i] += As[(rgrp + i * NGRP) * K + k] * b;  // LDS broadcast
        }
    }

#pragma unroll
    for (int i = 0; i < RPT; i++) {
        int r = row0 + rgrp + i * NGRP;
        if (r < n) C[(size_t)r * M + col] = acc[i];
    }
}

// ---------- edge scatter: agg[dst] += h[src] * dinv[src]*dinv[dst] ----------
// one thread per (edge, 4-feature chunk)
template<int M>
__global__ void scatter_kernel(const float4* __restrict__ h4, const int* __restrict__ src,
                               const int* __restrict__ dst, const float* __restrict__ dinv,
                               float* __restrict__ agg, int e) {
    constexpr int TPE = M / 4;
    long tid = (long)blockIdx.x * blockDim.x + threadIdx.x;
    if (tid >= (long)e * TPE) return;
    int edge = (int)(tid / TPE);
    int f4   = (int)(tid % TPE);
    int s = src[edge];
    int d = dst[edge];
    float nrm = dinv[s] * dinv[d];
    float4 v = h4[s * TPE + f4];
    float* out = agg + d * M + f4 * 4;
    atomicAdd(out + 0, v.x * nrm);
    atomicAdd(out + 1, v.y * nrm);
    atomicAdd(out + 2, v.z * nrm);
    atomicAdd(out + 3, v.w * nrm);
}

// ---------- epilogue: io += h*dinv^2 + bias, optional ReLU ----------
template<int M, bool RELU>
__global__ void epilogue_kernel(const float* __restrict__ h, const float* __restrict__ bias,
                                const float* __restrict__ dinv, float* __restrict__ io, int n) {
    int idx = blockIdx.x * blockDim.x + threadIdx.x;
    if (idx >= n * M) return;
    int node = idx / M;
    int f = idx - node * M;
    float di = dinv[node];
    float v = io[idx] + h[idx] * di * di + bias[f];
    io[idx] = RELU ? fmaxf(v, 0.0f) : v;
}

extern "C" void kernel_launch(void* const* d_in, const int* in_sizes, int n_in,
                              void* d_out, int out_size, void* d_ws, size_t ws_size,
                              hipStream_t stream) {
    const float* x  = (const float*)d_in[0];
    const float* W1 = (const float*)d_in[1];
    const float* b1 = (const float*)d_in[2];
    const float* W2 = (const float*)d_in[3];
    const float* b2 = (const float*)d_in[4];
    const int*   ei = (const int*)d_in[5];
    const int* src = ei;            // edge_index[0]
    const int* dst = ei + NEDGES;   // edge_index[1]
    float* out = (float*)d_out;

    float* ws   = (float*)d_ws;
    float* dinv = ws;                                   // N floats (padded)
    float* h1   = ws + 100352;                          // N*128 (reused as h2)
    float* agg1 = h1 + (size_t)NNODES * HIDD;           // N*128 (reused as hr)

    // zero accumulators
    hipMemsetAsync(agg1, 0, (size_t)NNODES * HIDD * sizeof(float), stream);
    hipMemsetAsync(out,  0, (size_t)NNODES * OUTD * sizeof(float), stream);

    // normalization
    init_deg<<<(NNODES + 255) / 256, 256, 0, stream>>>(dinv, NNODES);
    count_deg<<<(NEDGES + 255) / 256, 256, 0, stream>>>(dst, dinv, NEDGES);
    finalize_dinv<<<(NNODES + 255) / 256, 256, 0, stream>>>(dinv, NNODES);

    // layer 1: h1 = x @ W1
    gemm_kernel<IND, HIDD><<<(NNODES + 31) / 32, 256, 0, stream>>>(x, W1, h1, NNODES);
    // aggregate edges into agg1
    {
        long total = (long)NEDGES * (HIDD / 4);
        scatter_kernel<HIDD><<<(int)((total + 255) / 256), 256, 0, stream>>>(
            (const float4*)h1, src, dst, dinv, agg1, NEDGES);
    }
    // hr = relu(agg1 + h1*dinv^2 + b1)  (in-place in agg1)
    epilogue_kernel<HIDD, true><<<(NNODES * HIDD + 255) / 256, 256, 0, stream>>>(
        h1, b1, dinv, agg1, NNODES);

    // layer 2: h2 = hr @ W2   (h2 overwrites h1 buffer)
    gemm_kernel<HIDD, OUTD><<<(NNODES + 31) / 32, 256, 0, stream>>>(agg1, W2, h1, NNODES);
    // aggregate into d_out
    {
        long total = (long)NEDGES * (OUTD / 4);
        scatter_kernel<OUTD><<<(int)((total + 255) / 256), 256, 0, stream>>>(
            (const float4*)h1, src, dst, dinv, out, NEDGES);
    }
    // out += h2*dinv^2 + b2
    epilogue_kernel<OUTD, false><<<(NNODES * OUTD + 255) / 256, 256, 0, stream>>>(
        h1, b2, dinv, out, NNODES);
}

// Round 2
// 807.238 us; speedup vs baseline: 5.4339x; 5.4339x over previous
//
#include <hip/hip_runtime.h>

#define NNODES 100000
#define NEDGES 1600000
#define IND 128
#define HIDD 128
#define OUTD 64

// ---------- degree count (in-degree at dst) ----------
__global__ void count_deg(const int* __restrict__ dst, int* __restrict__ counts, int e) {
    int i = blockIdx.x * blockDim.x + threadIdx.x;
    if (i < e) atomicAdd(&counts[dst[i]], 1);
}

__global__ void finalize_dinv(const int* __restrict__ counts, float* __restrict__ dinv, int n) {
    int i = blockIdx.x * blockDim.x + threadIdx.x;
    if (i < n) dinv[i] = rsqrtf((float)(counts[i] + 1));   // +1 self-loop
}

// ---------- exclusive prefix scan (single block, 1024 threads) ----------
__global__ void scan_kernel(const int* __restrict__ counts, int* __restrict__ row_ptr, int n) {
    __shared__ int buf[1024];
    __shared__ int s_carry;
    const int tid = threadIdx.x;
    if (tid == 0) s_carry = 0;
    __syncthreads();
    for (int base = 0; base < n; base += 1024) {
        int v = (base + tid < n) ? counts[base + tid] : 0;
        buf[tid] = v;
        __syncthreads();
        // Hillis-Steele inclusive scan
        for (int off = 1; off < 1024; off <<= 1) {
            int t = (tid >= off) ? buf[tid - off] : 0;
            __syncthreads();
            buf[tid] += t;
            __syncthreads();
        }
        int c = s_carry;
        if (base + tid < n) row_ptr[base + tid] = c + buf[tid] - v;  // exclusive
        int total = buf[1023];
        __syncthreads();
        if (tid == 0) s_carry = c + total;
        __syncthreads();
    }
    if (tid == 0) row_ptr[n] = s_carry;
}

__global__ void copy_ptr(const int* __restrict__ row_ptr, int* __restrict__ cursor, int n) {
    int i = blockIdx.x * blockDim.x + threadIdx.x;
    if (i < n) cursor[i] = row_ptr[i];
}

// ---------- CSR fill: bucket edges by dst ----------
__global__ void fill_csr(const int* __restrict__ src, const int* __restrict__ dst,
                         int* __restrict__ cursor, int* __restrict__ csr_src, int e) {
    int i = blockIdx.x * blockDim.x + threadIdx.x;
    if (i < e) {
        int d = dst[i];
        int pos = atomicAdd(&cursor[d], 1);
        csr_src[pos] = src[i];
    }
}

// ---------- dense GEMM: C[n x M] = A[n x K] * W[K x M], row-major ----------
template<int K, int M>
__global__ void gemm_kernel(const float* __restrict__ A, const float* __restrict__ W,
                            float* __restrict__ C, int n) {
    __shared__ float As[32 * K];
    const int row0 = blockIdx.x * 32;

    for (int idx = threadIdx.x; idx < 32 * K; idx += 256) {
        int r = idx / K, k = idx % K;
        int gr = row0 + r;
        As[idx] = (gr < n) ? A[(size_t)gr * K + k] : 0.0f;
    }
    __syncthreads();

    constexpr int NGRP = 256 / M;
    constexpr int RPT  = 32 / NGRP;
    const int col  = threadIdx.x % M;
    const int rgrp = threadIdx.x / M;

    float acc[RPT];
#pragma unroll
    for (int i = 0; i < RPT; i++) acc[i] = 0.0f;

    for (int k = 0; k < K; k++) {
        float b = W[k * M + col];
#pragma unroll
        for (int i = 0; i < RPT; i++) {
            acc[i] += As[(rgrp + i * NGRP) * K + k] * b;
        }
    }

#pragma unroll
    for (int i = 0; i < RPT; i++) {
        int r = row0 + rgrp + i * NGRP;
        if (r < n) C[(size_t)r * M + col] = acc[i];
    }
}

// ---------- gather-aggregate per dst node ----------
// M features; LPG = M/4 lanes per node-group; GPB = 256/LPG nodes per block.
// out[v] = [relu]( sum_{s in N(v)} h[s]*dinv[s]*dinv[v] + h[v]*dinv[v]^2 + bias )
template<int M, bool RELU>
__launch_bounds__(256)
__global__ void gather_kernel(const float4* __restrict__ h4,
                              const int* __restrict__ row_ptr,
                              const int* __restrict__ csr_src,
                              const float* __restrict__ dinv,
                              const float* __restrict__ bias,
                              float4* __restrict__ out4, int n) {
    constexpr int LPG = M / 4;        // lanes per group
    constexpr int GPB = 256 / LPG;    // groups per block
    const int g = threadIdx.x / LPG;
    const int l = threadIdx.x % LPG;
    const int v = blockIdx.x * GPB + g;
    if (v >= n) return;

    const float dv = dinv[v];
    // self-loop contribution
    float4 self = h4[(size_t)v * LPG + l];
    float sn = dv * dv;
    float4 acc;
    acc.x = self.x * sn; acc.y = self.y * sn; acc.z = self.z * sn; acc.w = self.w * sn;

    int j   = row_ptr[v];
    int end = row_ptr[v + 1];
    for (; j + 1 < end; j += 2) {
        int s0 = csr_src[j];
        int s1 = csr_src[j + 1];
        float n0 = dinv[s0] * dv;
        float n1 = dinv[s1] * dv;
        float4 a = h4[(size_t)s0 * LPG + l];
        float4 b = h4[(size_t)s1 * LPG + l];
        acc.x += a.x * n0 + b.x * n1;
        acc.y += a.y * n0 + b.y * n1;
        acc.z += a.z * n0 + b.z * n1;
        acc.w += a.w * n0 + b.w * n1;
    }
    if (j < end) {
        int s0 = csr_src[j];
        float n0 = dinv[s0] * dv;
        float4 a = h4[(size_t)s0 * LPG + l];
        acc.x += a.x * n0; acc.y += a.y * n0; acc.z += a.z * n0; acc.w += a.w * n0;
    }

    acc.x += bias[l * 4 + 0];
    acc.y += bias[l * 4 + 1];
    acc.z += bias[l * 4 + 2];
    acc.w += bias[l * 4 + 3];
    if (RELU) {
        acc.x = fmaxf(acc.x, 0.0f); acc.y = fmaxf(acc.y, 0.0f);
        acc.z = fmaxf(acc.z, 0.0f); acc.w = fmaxf(acc.w, 0.0f);
    }
    out4[(size_t)v * LPG + l] = acc;
}

extern "C" void kernel_launch(void* const* d_in, const int* in_sizes, int n_in,
                              void* d_out, int out_size, void* d_ws, size_t ws_size,
                              hipStream_t stream) {
    const float* x  = (const float*)d_in[0];
    const float* W1 = (const float*)d_in[1];
    const float* b1 = (const float*)d_in[2];
    const float* W2 = (const float*)d_in[3];
    const float* b2 = (const float*)d_in[4];
    const int*   ei = (const int*)d_in[5];
    const int* src = ei;            // edge_index[0]
    const int* dst = ei + NEDGES;   // edge_index[1]
    float* out = (float*)d_out;

    // workspace layout (floats/ints are 4B):
    char* ws = (char*)d_ws;
    float* dinv    = (float*)ws;                         ws += (size_t)NNODES * 4;       // 0.4 MB
    int*   counts  = (int*)ws;                           ws += (size_t)NNODES * 4;       // 0.4 MB (reused as cursor)
    int*   row_ptr = (int*)ws;                           ws += (size_t)(NNODES + 4) * 4; // 0.4 MB
    int*   csr_src = (int*)ws;                           ws += (size_t)NEDGES * 4;       // 6.4 MB
    float* h1      = (float*)ws;                         ws += (size_t)NNODES * HIDD * 4;// 51.2 MB (reused as h2)
    float* hr      = (float*)ws;                                                         // 51.2 MB

    // ---- build normalization + CSR ----
    hipMemsetAsync(counts, 0, (size_t)NNODES * 4, stream);
    count_deg<<<(NEDGES + 255) / 256, 256, 0, stream>>>(dst, counts, NEDGES);
    finalize_dinv<<<(NNODES + 255) / 256, 256, 0, stream>>>(counts, dinv, NNODES);
    scan_kernel<<<1, 1024, 0, stream>>>(counts, row_ptr, NNODES);
    copy_ptr<<<(NNODES + 255) / 256, 256, 0, stream>>>(row_ptr, counts, NNODES); // counts = cursor
    fill_csr<<<(NEDGES + 255) / 256, 256, 0, stream>>>(src, dst, counts, csr_src, NEDGES);

    // ---- layer 1: h1 = x @ W1 ; hr = relu(Ahat @ h1 + b1) ----
    gemm_kernel<IND, HIDD><<<(NNODES + 31) / 32, 256, 0, stream>>>(x, W1, h1, NNODES);
    gather_kernel<HIDD, true><<<(NNODES * (HIDD / 4) + 255) / 256, 256, 0, stream>>>(
        (const float4*)h1, row_ptr, csr_src, dinv, b1, (float4*)hr, NNODES);

    // ---- layer 2: h2 = hr @ W2 ; out = Ahat @ h2 + b2 ----
    gemm_kernel<HIDD, OUTD><<<(NNODES + 31) / 32, 256, 0, stream>>>(hr, W2, h1, NNODES);
    gather_kernel<OUTD, false><<<(NNODES * (OUTD / 4) + 255) / 256, 256, 0, stream>>>(
        (const float4*)h1, row_ptr, csr_src, dinv, b2, (float4*)out, NNODES);
}

// Round 3
// 641.372 us; speedup vs baseline: 6.8392x; 1.2586x over previous
//
#include <hip/hip_runtime.h>

#define NNODES 100000
#define NEDGES 1600000
#define IND 128
#define HIDD 128
#define OUTD 64
#define SCAN_BLK 1024
#define NSCAN ((NNODES + SCAN_BLK - 1) / SCAN_BLK)   // 98

// ---------- degree count (in-degree at dst) ----------
__global__ void count_deg(const int* __restrict__ dst, int* __restrict__ counts, int e) {
    int i = blockIdx.x * blockDim.x + threadIdx.x;
    if (i < e) atomicAdd(&counts[dst[i]], 1);
}

__global__ void finalize_dinv(const int* __restrict__ counts, float* __restrict__ dinv, int n) {
    int i = blockIdx.x * blockDim.x + threadIdx.x;
    if (i < n) dinv[i] = rsqrtf((float)(counts[i] + 1));   // +1 self-loop
}

// ---------- 3-phase parallel exclusive scan ----------
// Phase A: per-block exclusive scan, write block sums
__global__ void scan_phase_a(const int* __restrict__ counts, int* __restrict__ row_ptr,
                             int* __restrict__ blk_sums, int n) {
    __shared__ int buf[SCAN_BLK];
    const int tid = threadIdx.x;
    const int gid = blockIdx.x * SCAN_BLK + tid;
    int v = (gid < n) ? counts[gid] : 0;
    buf[tid] = v;
    __syncthreads();
    for (int off = 1; off < SCAN_BLK; off <<= 1) {
        int t = (tid >= off) ? buf[tid - off] : 0;
        __syncthreads();
        buf[tid] += t;
        __syncthreads();
    }
    if (gid < n) row_ptr[gid] = buf[tid] - v;          // exclusive within block
    if (tid == SCAN_BLK - 1) blk_sums[blockIdx.x] = buf[tid];
}

// Phase B: single small block scans block sums (nb <= 128)
__global__ void scan_phase_b(const int* __restrict__ blk_sums, int* __restrict__ blk_offsets, int nb) {
    __shared__ int buf[128];
    const int tid = threadIdx.x;
    int v = (tid < nb) ? blk_sums[tid] : 0;
    buf[tid] = v;
    __syncthreads();
    for (int off = 1; off < 128; off <<= 1) {
        int t = (tid >= off) ? buf[tid - off] : 0;
        __syncthreads();
        buf[tid] += t;
        __syncthreads();
    }
    if (tid < nb) blk_offsets[tid] = buf[tid] - v;      // exclusive
}

// Phase C: add block offsets, set sentinel, init cursor copy
__global__ void scan_phase_c(int* __restrict__ row_ptr, const int* __restrict__ blk_offsets,
                             int* __restrict__ cursor, int n) {
    int gid = blockIdx.x * blockDim.x + threadIdx.x;
    if (gid < n) {
        int rp = row_ptr[gid] + blk_offsets[gid >> 10];
        row_ptr[gid] = rp;
        cursor[gid] = rp;
    }
    if (gid == 0) row_ptr[n] = NEDGES;
}

// ---------- CSR fill: bucket edges by dst ----------
__global__ void fill_csr(const int* __restrict__ src, const int* __restrict__ dst,
                         int* __restrict__ cursor, int* __restrict__ csr_src, int e) {
    int i = blockIdx.x * blockDim.x + threadIdx.x;
    if (i < e) {
        int d = dst[i];
        int pos = atomicAdd(&cursor[d], 1);
        csr_src[pos] = src[i];
    }
}

// ---------- dense GEMM: C[n x M] = A[n x K] * W[K x M], row-major ----------
template<int K, int M>
__global__ void gemm_kernel(const float* __restrict__ A, const float* __restrict__ W,
                            float* __restrict__ C, int n) {
    __shared__ float As[32 * K];
    const int row0 = blockIdx.x * 32;

    for (int idx = threadIdx.x; idx < 32 * K; idx += 256) {
        int r = idx / K, k = idx % K;
        int gr = row0 + r;
        As[idx] = (gr < n) ? A[(size_t)gr * K + k] : 0.0f;
    }
    __syncthreads();

    constexpr int NGRP = 256 / M;
    constexpr int RPT  = 32 / NGRP;
    const int col  = threadIdx.x % M;
    const int rgrp = threadIdx.x / M;

    float acc[RPT];
#pragma unroll
    for (int i = 0; i < RPT; i++) acc[i] = 0.0f;

    for (int k = 0; k < K; k++) {
        float b = W[k * M + col];
#pragma unroll
        for (int i = 0; i < RPT; i++) {
            acc[i] += As[(rgrp + i * NGRP) * K + k] * b;
        }
    }

#pragma unroll
    for (int i = 0; i < RPT; i++) {
        int r = row0 + rgrp + i * NGRP;
        if (r < n) C[(size_t)r * M + col] = acc[i];
    }
}

// ---------- gather-aggregate per dst node ----------
template<int M, bool RELU>
__launch_bounds__(256)
__global__ void gather_kernel(const float4* __restrict__ h4,
                              const int* __restrict__ row_ptr,
                              const int* __restrict__ csr_src,
                              const float* __restrict__ dinv,
                              const float* __restrict__ bias,
                              float4* __restrict__ out4, int n) {
    constexpr int LPG = M / 4;        // lanes per group
    constexpr int GPB = 256 / LPG;    // groups per block
    const int g = threadIdx.x / LPG;
    const int l = threadIdx.x % LPG;
    const int v = blockIdx.x * GPB + g;
    if (v >= n) return;

    const float dv = dinv[v];
    float4 self = h4[(size_t)v * LPG + l];
    float sn = dv * dv;
    float4 acc;
    acc.x = self.x * sn; acc.y = self.y * sn; acc.z = self.z * sn; acc.w = self.w * sn;

    int j   = row_ptr[v];
    int end = row_ptr[v + 1];
    for (; j + 1 < end; j += 2) {
        int s0 = csr_src[j];
        int s1 = csr_src[j + 1];
        float n0 = dinv[s0] * dv;
        float n1 = dinv[s1] * dv;
        float4 a = h4[(size_t)s0 * LPG + l];
        float4 b = h4[(size_t)s1 * LPG + l];
        acc.x += a.x * n0 + b.x * n1;
        acc.y += a.y * n0 + b.y * n1;
        acc.z += a.z * n0 + b.z * n1;
        acc.w += a.w * n0 + b.w * n1;
    }
    if (j < end) {
        int s0 = csr_src[j];
        float n0 = dinv[s0] * dv;
        float4 a = h4[(size_t)s0 * LPG + l];
        acc.x += a.x * n0; acc.y += a.y * n0; acc.z += a.z * n0; acc.w += a.w * n0;
    }

    acc.x += bias[l * 4 + 0];
    acc.y += bias[l * 4 + 1];
    acc.z += bias[l * 4 + 2];
    acc.w += bias[l * 4 + 3];
    if (RELU) {
        acc.x = fmaxf(acc.x, 0.0f); acc.y = fmaxf(acc.y, 0.0f);
        acc.z = fmaxf(acc.z, 0.0f); acc.w = fmaxf(acc.w, 0.0f);
    }
    out4[(size_t)v * LPG + l] = acc;
}

extern "C" void kernel_launch(void* const* d_in, const int* in_sizes, int n_in,
                              void* d_out, int out_size, void* d_ws, size_t ws_size,
                              hipStream_t stream) {
    const float* x  = (const float*)d_in[0];
    const float* W1 = (const float*)d_in[1];
    const float* b1 = (const float*)d_in[2];
    const float* W2 = (const float*)d_in[3];
    const float* b2 = (const float*)d_in[4];
    const int*   ei = (const int*)d_in[5];
    const int* src = ei;            // edge_index[0]
    const int* dst = ei + NEDGES;   // edge_index[1]
    float* out = (float*)d_out;

    // workspace layout:
    char* ws = (char*)d_ws;
    float* dinv     = (float*)ws;   ws += (size_t)NNODES * 4;
    int*   counts   = (int*)ws;     ws += (size_t)NNODES * 4;        // reused as cursor
    int*   row_ptr  = (int*)ws;     ws += (size_t)(NNODES + 4) * 4;
    int*   blk_sums = (int*)ws;     ws += 128 * 4;
    int*   blk_offs = (int*)ws;     ws += 128 * 4;
    int*   csr_src  = (int*)ws;     ws += (size_t)NEDGES * 4;
    float* h1       = (float*)ws;   ws += (size_t)NNODES * HIDD * 4; // reused as h2
    float* hr       = (float*)ws;

    // ---- build normalization + CSR ----
    hipMemsetAsync(counts, 0, (size_t)NNODES * 4, stream);
    count_deg<<<(NEDGES + 255) / 256, 256, 0, stream>>>(dst, counts, NEDGES);
    finalize_dinv<<<(NNODES + 255) / 256, 256, 0, stream>>>(counts, dinv, NNODES);
    scan_phase_a<<<NSCAN, SCAN_BLK, 0, stream>>>(counts, row_ptr, blk_sums, NNODES);
    scan_phase_b<<<1, 128, 0, stream>>>(blk_sums, blk_offs, NSCAN);
    scan_phase_c<<<(NNODES + 255) / 256, 256, 0, stream>>>(row_ptr, blk_offs, counts, NNODES);
    fill_csr<<<(NEDGES + 255) / 256, 256, 0, stream>>>(src, dst, counts, csr_src, NEDGES);

    // ---- layer 1: h1 = x @ W1 ; hr = relu(Ahat @ h1 + b1) ----
    gemm_kernel<IND, HIDD><<<(NNODES + 31) / 32, 256, 0, stream>>>(x, W1, h1, NNODES);
    gather_kernel<HIDD, true><<<(NNODES * (HIDD / 4) + 255) / 256, 256, 0, stream>>>(
        (const float4*)h1, row_ptr, csr_src, dinv, b1, (float4*)hr, NNODES);

    // ---- layer 2: h2 = hr @ W2 ; out = Ahat @ h2 + b2 ----
    gemm_kernel<HIDD, OUTD><<<(NNODES + 31) / 32, 256, 0, stream>>>(hr, W2, h1, NNODES);
    gather_kernel<OUTD, false><<<(NNODES * (OUTD / 4) + 255) / 256, 256, 0, stream>>>(
        (const float4*)h1, row_ptr, csr_src, dinv, b2, (float4*)out, NNODES);
}

// Round 4
// 565.025 us; speedup vs baseline: 7.7633x; 1.1351x over previous
//
#include <hip/hip_runtime.h>

#define NNODES 100000
#define NEDGES 1600000
#define IND 128
#define HIDD 128
#define OUTD 64
#define SCAN_BLK 1024
#define NSCAN ((NNODES + SCAN_BLK - 1) / SCAN_BLK)   // 98

typedef unsigned int  uint32;
typedef unsigned short ushort16;

// ---------- bf16 helpers ----------
__device__ __forceinline__ unsigned short f2bf(float f) {
    union { float f; uint32 u; } x; x.f = f;
    uint32 u = x.u;
    return (unsigned short)((u + 0x7fffu + ((u >> 16) & 1u)) >> 16);   // RNE
}
__device__ __forceinline__ float bflo(uint32 u) {
    union { uint32 i; float f; } x; x.i = u << 16; return x.f;
}
__device__ __forceinline__ float bfhi(uint32 u) {
    union { uint32 i; float f; } x; x.i = u & 0xffff0000u; return x.f;
}

// ---------- degree count (in-degree at dst) ----------
__global__ void count_deg(const int* __restrict__ dst, int* __restrict__ counts, int e) {
    int i = blockIdx.x * blockDim.x + threadIdx.x;
    if (i < e) atomicAdd(&counts[dst[i]], 1);
}

__global__ void finalize_dinv(const int* __restrict__ counts, float* __restrict__ dinv, int n) {
    int i = blockIdx.x * blockDim.x + threadIdx.x;
    if (i < n) dinv[i] = rsqrtf((float)(counts[i] + 1));   // +1 self-loop
}

// ---------- 3-phase parallel exclusive scan ----------
__global__ void scan_phase_a(const int* __restrict__ counts, int* __restrict__ row_ptr,
                             int* __restrict__ blk_sums, int n) {
    __shared__ int buf[SCAN_BLK];
    const int tid = threadIdx.x;
    const int gid = blockIdx.x * SCAN_BLK + tid;
    int v = (gid < n) ? counts[gid] : 0;
    buf[tid] = v;
    __syncthreads();
    for (int off = 1; off < SCAN_BLK; off <<= 1) {
        int t = (tid >= off) ? buf[tid - off] : 0;
        __syncthreads();
        buf[tid] += t;
        __syncthreads();
    }
    if (gid < n) row_ptr[gid] = buf[tid] - v;
    if (tid == SCAN_BLK - 1) blk_sums[blockIdx.x] = buf[tid];
}

__global__ void scan_phase_b(const int* __restrict__ blk_sums, int* __restrict__ blk_offsets, int nb) {
    __shared__ int buf[128];
    const int tid = threadIdx.x;
    int v = (tid < nb) ? blk_sums[tid] : 0;
    buf[tid] = v;
    __syncthreads();
    for (int off = 1; off < 128; off <<= 1) {
        int t = (tid >= off) ? buf[tid - off] : 0;
        __syncthreads();
        buf[tid] += t;
        __syncthreads();
    }
    if (tid < nb) blk_offsets[tid] = buf[tid] - v;
}

__global__ void scan_phase_c(int* __restrict__ row_ptr, const int* __restrict__ blk_offsets,
                             int* __restrict__ cursor, int n) {
    int gid = blockIdx.x * blockDim.x + threadIdx.x;
    if (gid < n) {
        int rp = row_ptr[gid] + blk_offsets[gid >> 10];
        row_ptr[gid] = rp;
        cursor[gid] = rp;
    }
    if (gid == 0) row_ptr[n] = NEDGES;
}

// ---------- CSR fill ----------
__global__ void fill_csr(const int* __restrict__ src, const int* __restrict__ dst,
                         int* __restrict__ cursor, int* __restrict__ csr_src, int e) {
    int i = blockIdx.x * blockDim.x + threadIdx.x;
    if (i < e) {
        int d = dst[i];
        int pos = atomicAdd(&cursor[d], 1);
        csr_src[pos] = src[i];
    }
}

// ---------- register-tiled fp32 GEMM, bf16 output ----------
// C[n x M](bf16) = A[n x K](f32) * W[K x M](f32)
// 256 threads; per-thread 8x8 outputs; BR = (256/(M/8))*8 rows per block; BK=32.
template<int K, int M>
__global__ void gemm_bf16out(const float* __restrict__ A, const float* __restrict__ W,
                             ushort16* __restrict__ C, int n) {
    constexpr int CG = M / 8;            // col groups (16 or 8)
    constexpr int BR = (256 / CG) * 8;   // 128 (M=128) or 256 (M=64)
    __shared__ float As[BR * 32];        // [BR][32]
    __shared__ float Ws[32 * M];         // [32][M]

    const int tx = threadIdx.x % CG;
    const int ty = threadIdx.x / CG;
    const int row0 = blockIdx.x * BR;

    float acc[8][8];
#pragma unroll
    for (int r = 0; r < 8; r++)
#pragma unroll
        for (int c = 0; c < 8; c++) acc[r][c] = 0.0f;

    float4* Asf4 = (float4*)As;
    float4* Wsf4 = (float4*)Ws;

    for (int kc = 0; kc < K; kc += 32) {
        // stage A tile: BR x 32 floats = BR*8 float4
#pragma unroll
        for (int i = 0; i < BR / 32; i++) {
            int idx = threadIdx.x + i * 256;           // = row*8 + kq
            int row = idx >> 3, kq = idx & 7;
            int grow = row0 + row;
            if (grow >= n) grow = n - 1;
            Asf4[idx] = *(const float4*)(A + (size_t)grow * K + kc + kq * 4);
        }
        // stage W tile: 32 x M floats (contiguous region)
#pragma unroll
        for (int i = 0; i < (32 * M / 4) / 256; i++) {
            int idx = threadIdx.x + i * 256;
            Wsf4[idx] = ((const float4*)(W + (size_t)kc * M))[idx];
        }
        __syncthreads();

#pragma unroll
        for (int kk0 = 0; kk0 < 32; kk0 += 4) {
            float4 a[8];
#pragma unroll
            for (int r = 0; r < 8; r++)
                a[r] = Asf4[(ty * 8 + r) * 8 + (kk0 >> 2)];
#pragma unroll
            for (int j = 0; j < 4; j++) {
                int base = (kk0 + j) * (M / 4) + tx * 2;
                float4 w0 = Wsf4[base];
                float4 w1 = Wsf4[base + 1];
#pragma unroll
                for (int r = 0; r < 8; r++) {
                    float av = (j == 0) ? a[r].x : (j == 1) ? a[r].y : (j == 2) ? a[r].z : a[r].w;
                    acc[r][0] += av * w0.x; acc[r][1] += av * w0.y;
                    acc[r][2] += av * w0.z; acc[r][3] += av * w0.w;
                    acc[r][4] += av * w1.x; acc[r][5] += av * w1.y;
                    acc[r][6] += av * w1.z; acc[r][7] += av * w1.w;
                }
            }
        }
        __syncthreads();
    }

    // store 8 rows x 8 bf16
#pragma unroll
    for (int r = 0; r < 8; r++) {
        int grow = row0 + ty * 8 + r;
        if (grow < n) {
            uint32 p[4];
#pragma unroll
            for (int c = 0; c < 4; c++)
                p[c] = (uint32)f2bf(acc[r][2 * c]) | ((uint32)f2bf(acc[r][2 * c + 1]) << 16);
            uint4 val = make_uint4(p[0], p[1], p[2], p[3]);
            *(uint4*)(C + (size_t)grow * M + tx * 8) = val;
        }
    }
}

// ---------- gather-aggregate, bf16 input, f32 output ----------
// LPG = M/8 lanes per node; each lane owns 8 features (one 16B load per neighbor).
template<int M, bool RELU>
__launch_bounds__(256)
__global__ void gather_bf16(const ushort16* __restrict__ h,
                            const int* __restrict__ row_ptr,
                            const int* __restrict__ csr_src,
                            const float* __restrict__ dinv,
                            const float* __restrict__ bias,
                            float* __restrict__ outp, int n) {
    constexpr int LPG = M / 8;
    constexpr int GPB = 256 / LPG;
    const int g = threadIdx.x / LPG;
    const int l = threadIdx.x % LPG;
    const int v = blockIdx.x * GPB + g;
    if (v >= n) return;

    const float dv = dinv[v];
    float acc[8];

    // self-loop
    {
        uint4 u = *(const uint4*)(h + (size_t)v * M + l * 8);
        float sn = dv * dv;
        acc[0] = bflo(u.x) * sn; acc[1] = bfhi(u.x) * sn;
        acc[2] = bflo(u.y) * sn; acc[3] = bfhi(u.y) * sn;
        acc[4] = bflo(u.z) * sn; acc[5] = bfhi(u.z) * sn;
        acc[6] = bflo(u.w) * sn; acc[7] = bfhi(u.w) * sn;
    }

    int j   = row_ptr[v];
    int end = row_ptr[v + 1];
    for (; j + 1 < end; j += 2) {
        int s0 = csr_src[j];
        int s1 = csr_src[j + 1];
        float n0 = dinv[s0] * dv;
        float n1 = dinv[s1] * dv;
        uint4 ua = *(const uint4*)(h + (size_t)s0 * M + l * 8);
        uint4 ub = *(const uint4*)(h + (size_t)s1 * M + l * 8);
        acc[0] += bflo(ua.x) * n0 + bflo(ub.x) * n1;
        acc[1] += bfhi(ua.x) * n0 + bfhi(ub.x) * n1;
        acc[2] += bflo(ua.y) * n0 + bflo(ub.y) * n1;
        acc[3] += bfhi(ua.y) * n0 + bfhi(ub.y) * n1;
        acc[4] += bflo(ua.z) * n0 + bflo(ub.z) * n1;
        acc[5] += bfhi(ua.z) * n0 + bfhi(ub.z) * n1;
        acc[6] += bflo(ua.w) * n0 + bflo(ub.w) * n1;
        acc[7] += bfhi(ua.w) * n0 + bfhi(ub.w) * n1;
    }
    if (j < end) {
        int s0 = csr_src[j];
        float n0 = dinv[s0] * dv;
        uint4 ua = *(const uint4*)(h + (size_t)s0 * M + l * 8);
        acc[0] += bflo(ua.x) * n0; acc[1] += bfhi(ua.x) * n0;
        acc[2] += bflo(ua.y) * n0; acc[3] += bfhi(ua.y) * n0;
        acc[4] += bflo(ua.z) * n0; acc[5] += bfhi(ua.z) * n0;
        acc[6] += bflo(ua.w) * n0; acc[7] += bfhi(ua.w) * n0;
    }

#pragma unroll
    for (int i = 0; i < 8; i++) {
        acc[i] += bias[l * 8 + i];
        if (RELU) acc[i] = fmaxf(acc[i], 0.0f);
    }
    float4 o0 = make_float4(acc[0], acc[1], acc[2], acc[3]);
    float4 o1 = make_float4(acc[4], acc[5], acc[6], acc[7]);
    float* op = outp + (size_t)v * M + l * 8;
    *(float4*)op = o0;
    *(float4*)(op + 4) = o1;
}

extern "C" void kernel_launch(void* const* d_in, const int* in_sizes, int n_in,
                              void* d_out, int out_size, void* d_ws, size_t ws_size,
                              hipStream_t stream) {
    const float* x  = (const float*)d_in[0];
    const float* W1 = (const float*)d_in[1];
    const float* b1 = (const float*)d_in[2];
    const float* W2 = (const float*)d_in[3];
    const float* b2 = (const float*)d_in[4];
    const int*   ei = (const int*)d_in[5];
    const int* src = ei;            // edge_index[0]
    const int* dst = ei + NEDGES;   // edge_index[1]
    float* out = (float*)d_out;

    // workspace layout (all offsets 16B-aligned):
    char* ws = (char*)d_ws;
    float* dinv     = (float*)ws;   ws += (size_t)NNODES * 4;
    int*   counts   = (int*)ws;     ws += (size_t)NNODES * 4;        // reused as cursor
    int*   row_ptr  = (int*)ws;     ws += (size_t)(NNODES + 4) * 4;
    int*   blk_sums = (int*)ws;     ws += 128 * 4;
    int*   blk_offs = (int*)ws;     ws += 128 * 4;
    int*   csr_src  = (int*)ws;     ws += (size_t)NEDGES * 4;
    float* hr       = (float*)ws;   ws += (size_t)NNODES * HIDD * 4; // f32 relu output
    ushort16* hbf   = (ushort16*)ws;                                 // bf16 h1 (reused as h2)

    // ---- build normalization + CSR ----
    hipMemsetAsync(counts, 0, (size_t)NNODES * 4, stream);
    count_deg<<<(NEDGES + 255) / 256, 256, 0, stream>>>(dst, counts, NEDGES);
    finalize_dinv<<<(NNODES + 255) / 256, 256, 0, stream>>>(counts, dinv, NNODES);
    scan_phase_a<<<NSCAN, SCAN_BLK, 0, stream>>>(counts, row_ptr, blk_sums, NNODES);
    scan_phase_b<<<1, 128, 0, stream>>>(blk_sums, blk_offs, NSCAN);
    scan_phase_c<<<(NNODES + 255) / 256, 256, 0, stream>>>(row_ptr, blk_offs, counts, NNODES);
    fill_csr<<<(NEDGES + 255) / 256, 256, 0, stream>>>(src, dst, counts, csr_src, NEDGES);

    // ---- layer 1: h1(bf16) = x @ W1 ; hr = relu(Ahat @ h1 + b1) ----
    gemm_bf16out<IND, HIDD><<<(NNODES + 127) / 128, 256, 0, stream>>>(x, W1, hbf, NNODES);
    gather_bf16<HIDD, true><<<(NNODES * (HIDD / 8) + 255) / 256, 256, 0, stream>>>(
        hbf, row_ptr, csr_src, dinv, b1, hr, NNODES);

    // ---- layer 2: h2(bf16) = hr @ W2 ; out = Ahat @ h2 + b2 ----
    gemm_bf16out<HIDD, OUTD><<<(NNODES + 255) / 256, 256, 0, stream>>>(hr, W2, hbf, NNODES);
    gather_bf16<OUTD, false><<<(NNODES * (OUTD / 8) + 255) / 256, 256, 0, stream>>>(
        hbf, row_ptr, csr_src, dinv, b2, out, NNODES);
}

// Round 5
// 444.523 us; speedup vs baseline: 9.8678x; 1.2711x over previous
//
#include <hip/hip_runtime.h>

#define NNODES 100000
#define NEDGES 1600000
#define IND 128
#define HIDD 128
#define OUTD 64
#define SCAN_BLK 1024
#define NSCAN ((NNODES + SCAN_BLK - 1) / SCAN_BLK)   // 98

// bucketed CSR build
#define BSHIFT 9
#define BSIZE  512
#define NBUCK  ((NNODES + BSIZE - 1) / BSIZE)        // 196
#define HIST_EPB 8192
#define BIN_EPB  4096
#define SEG_CAP  10240

typedef unsigned int  uint32;
typedef unsigned short ushort16;

// ---------- bf16 helpers ----------
__device__ __forceinline__ unsigned short f2bf(float f) {
    union { float f; uint32 u; } x; x.f = f;
    uint32 u = x.u;
    return (unsigned short)((u + 0x7fffu + ((u >> 16) & 1u)) >> 16);   // RNE
}
__device__ __forceinline__ float bflo(uint32 u) {
    union { uint32 i; float f; } x; x.i = u << 16; return x.f;
}
__device__ __forceinline__ float bfhi(uint32 u) {
    union { uint32 i; float f; } x; x.i = u & 0xffff0000u; return x.f;
}

// ---------- phase A: bucket histogram (LDS-aggregated) ----------
__global__ void k_hist(const int* __restrict__ dst, int* __restrict__ bcounts, int e) {
    __shared__ int lh[NBUCK];
    for (int i = threadIdx.x; i < NBUCK; i += 256) lh[i] = 0;
    __syncthreads();
    int start = blockIdx.x * HIST_EPB;
    int end = min(start + HIST_EPB, e);
    for (int i = start + threadIdx.x; i < end; i += 256)
        atomicAdd(&lh[dst[i] >> BSHIFT], 1);
    __syncthreads();
    for (int i = threadIdx.x; i < NBUCK; i += 256)
        if (lh[i]) atomicAdd(&bcounts[i], lh[i]);
}

// ---------- phase B: scan bucket counts (1 block) ----------
__global__ void k_bscan(const int* __restrict__ bcounts, int* __restrict__ boff,
                        int* __restrict__ bcur) {
    __shared__ int buf[256];
    const int tid = threadIdx.x;
    int v = (tid < NBUCK) ? bcounts[tid] : 0;
    buf[tid] = v;
    __syncthreads();
    for (int off = 1; off < 256; off <<= 1) {
        int t = (tid >= off) ? buf[tid - off] : 0;
        __syncthreads();
        buf[tid] += t;
        __syncthreads();
    }
    if (tid < NBUCK) { int ex = buf[tid] - v; boff[tid] = ex; bcur[tid] = ex; }
    if (tid == 255) boff[NBUCK] = buf[255];
}

// ---------- phase C: bin (src,dst) pairs into bucket-contiguous staging ----------
__global__ void k_bin(const int* __restrict__ src, const int* __restrict__ dst,
                      int* __restrict__ bcur, uint2* __restrict__ staging, int e) {
    __shared__ int lh[NBUCK];      // per-bucket count in this block
    __shared__ int lbase[NBUCK];   // exclusive scan
    __shared__ int lcur[NBUCK];    // scatter cursor
    __shared__ int gbase[NBUCK];   // global base in staging
    __shared__ int sbuf[256];
    __shared__ uint2 lp[BIN_EPB];  // 32 KB

    const int tid = threadIdx.x;
    for (int i = tid; i < NBUCK; i += 256) lh[i] = 0;
    __syncthreads();

    int start = blockIdx.x * BIN_EPB;
    int end = min(start + BIN_EPB, e);
    int n = end - start;

    for (int i = start + tid; i < end; i += 256)
        atomicAdd(&lh[dst[i] >> BSHIFT], 1);
    __syncthreads();

    // exclusive scan of lh (NBUCK <= 256)
    int v = (tid < NBUCK) ? lh[tid] : 0;
    sbuf[tid] = v;
    __syncthreads();
    for (int off = 1; off < 256; off <<= 1) {
        int t = (tid >= off) ? sbuf[tid - off] : 0;
        __syncthreads();
        sbuf[tid] += t;
        __syncthreads();
    }
    if (tid < NBUCK) { int ex = sbuf[tid] - v; lbase[tid] = ex; lcur[tid] = ex; }
    __syncthreads();

    // scatter pairs into LDS, bucket-contiguous
    for (int i = start + tid; i < end; i += 256) {
        int d = dst[i], s = src[i];
        int b = d >> BSHIFT;
        int pos = atomicAdd(&lcur[b], 1);
        lp[pos] = make_uint2((uint32)s, (uint32)d);
    }
    // reserve global space per bucket
    if (tid < NBUCK) {
        int c = lh[tid];
        gbase[tid] = c ? atomicAdd(&bcur[tid], c) : 0;
    }
    __syncthreads();

    // run-write to staging (runs of ~21 pairs are line-efficient)
    for (int i = tid; i < n; i += 256) {
        uint2 p = lp[i];
        int b = (int)(p.y >> BSHIFT);
        staging[gbase[b] + (i - lbase[b])] = p;
    }
}

// ---------- phase D: per-node in-degree from staging (coalesced writes) ----------
__global__ void k_ncount(const uint2* __restrict__ staging, const int* __restrict__ boff,
                         int* __restrict__ counts, int n) {
    __shared__ int nc[BSIZE];
    const int b = blockIdx.x;
    const int base = b << BSHIFT;
    const int tid = threadIdx.x;
    for (int i = tid; i < BSIZE; i += 256) nc[i] = 0;
    __syncthreads();
    int s0 = boff[b], s1 = boff[b + 1];
    for (int i = s0 + tid; i < s1; i += 256)
        atomicAdd(&nc[staging[i].y - base], 1);
    __syncthreads();
    for (int i = tid; i < BSIZE; i += 256) {
        int node = base + i;
        if (node < n) counts[node] = nc[i];
    }
}

__global__ void finalize_dinv(const int* __restrict__ counts, float* __restrict__ dinv, int n) {
    int i = blockIdx.x * blockDim.x + threadIdx.x;
    if (i < n) dinv[i] = rsqrtf((float)(counts[i] + 1));   // +1 self-loop
}

// ---------- 3-phase parallel exclusive scan (row_ptr) ----------
__global__ void scan_phase_a(const int* __restrict__ counts, int* __restrict__ row_ptr,
                             int* __restrict__ blk_sums, int n) {
    __shared__ int buf[SCAN_BLK];
    const int tid = threadIdx.x;
    const int gid = blockIdx.x * SCAN_BLK + tid;
    int v = (gid < n) ? counts[gid] : 0;
    buf[tid] = v;
    __syncthreads();
    for (int off = 1; off < SCAN_BLK; off <<= 1) {
        int t = (tid >= off) ? buf[tid - off] : 0;
        __syncthreads();
        buf[tid] += t;
        __syncthreads();
    }
    if (gid < n) row_ptr[gid] = buf[tid] - v;
    if (tid == SCAN_BLK - 1) blk_sums[blockIdx.x] = buf[tid];
}

__global__ void scan_phase_b(const int* __restrict__ blk_sums, int* __restrict__ blk_offsets, int nb) {
    __shared__ int buf[128];
    const int tid = threadIdx.x;
    int v = (tid < nb) ? blk_sums[tid] : 0;
    buf[tid] = v;
    __syncthreads();
    for (int off = 1; off < 128; off <<= 1) {
        int t = (tid >= off) ? buf[tid - off] : 0;
        __syncthreads();
        buf[tid] += t;
        __syncthreads();
    }
    if (tid < nb) blk_offsets[tid] = buf[tid] - v;
}

__global__ void scan_phase_c(int* __restrict__ row_ptr, const int* __restrict__ blk_offsets, int n) {
    int gid = blockIdx.x * blockDim.x + threadIdx.x;
    if (gid < n) row_ptr[gid] += blk_offsets[gid >> 10];
    if (gid == 0) row_ptr[n] = NEDGES;
}

// ---------- phase E: per-bucket counting-sort in LDS -> coalesced csr_src ----------
__global__ void k_fill2(const uint2* __restrict__ staging, const int* __restrict__ boff,
                        const int* __restrict__ row_ptr, int* __restrict__ csr_src, int n) {
    __shared__ int lcur[BSIZE];
    __shared__ int seg[SEG_CAP];   // 40 KB
    const int b = blockIdx.x;
    const int base = b << BSHIFT;
    const int tid = threadIdx.x;
    const int nn = min(BSIZE, n - base);
    const int r0 = row_ptr[base];
    for (int i = tid; i < nn; i += 256) lcur[i] = row_ptr[base + i] - r0;
    __syncthreads();
    const int L = row_ptr[base + nn] - r0;
    int s0 = boff[b], s1 = boff[b + 1];
    for (int i = s0 + tid; i < s1; i += 256) {
        uint2 p = staging[i];
        int pos = atomicAdd(&lcur[p.y - base], 1);
        if (pos < SEG_CAP) seg[pos] = (int)p.x;
        else               csr_src[r0 + pos] = (int)p.x;   // overflow fallback
    }
    __syncthreads();
    int lim = min(L, SEG_CAP);
    for (int i = tid; i < lim; i += 256) csr_src[r0 + i] = seg[i];
}

// ---------- register-tiled fp32 GEMM, bf16 output ----------
template<int K, int M>
__global__ void gemm_bf16out(const float* __restrict__ A, const float* __restrict__ W,
                             ushort16* __restrict__ C, int n) {
    constexpr int CG = M / 8;
    constexpr int BR = (256 / CG) * 8;
    __shared__ float As[BR * 32];
    __shared__ float Ws[32 * M];

    const int tx = threadIdx.x % CG;
    const int ty = threadIdx.x / CG;
    const int row0 = blockIdx.x * BR;

    float acc[8][8];
#pragma unroll
    for (int r = 0; r < 8; r++)
#pragma unroll
        for (int c = 0; c < 8; c++) acc[r][c] = 0.0f;

    float4* Asf4 = (float4*)As;
    float4* Wsf4 = (float4*)Ws;

    for (int kc = 0; kc < K; kc += 32) {
#pragma unroll
        for (int i = 0; i < BR / 32; i++) {
            int idx = threadIdx.x + i * 256;
            int row = idx >> 3, kq = idx & 7;
            int grow = row0 + row;
            if (grow >= n) grow = n - 1;
            Asf4[idx] = *(const float4*)(A + (size_t)grow * K + kc + kq * 4);
        }
#pragma unroll
        for (int i = 0; i < (32 * M / 4) / 256; i++) {
            int idx = threadIdx.x + i * 256;
            Wsf4[idx] = ((const float4*)(W + (size_t)kc * M))[idx];
        }
        __syncthreads();

#pragma unroll
        for (int kk0 = 0; kk0 < 32; kk0 += 4) {
            float4 a[8];
#pragma unroll
            for (int r = 0; r < 8; r++)
                a[r] = Asf4[(ty * 8 + r) * 8 + (kk0 >> 2)];
#pragma unroll
            for (int j = 0; j < 4; j++) {
                int base = (kk0 + j) * (M / 4) + tx * 2;
                float4 w0 = Wsf4[base];
                float4 w1 = Wsf4[base + 1];
#pragma unroll
                for (int r = 0; r < 8; r++) {
                    float av = (j == 0) ? a[r].x : (j == 1) ? a[r].y : (j == 2) ? a[r].z : a[r].w;
                    acc[r][0] += av * w0.x; acc[r][1] += av * w0.y;
                    acc[r][2] += av * w0.z; acc[r][3] += av * w0.w;
                    acc[r][4] += av * w1.x; acc[r][5] += av * w1.y;
                    acc[r][6] += av * w1.z; acc[r][7] += av * w1.w;
                }
            }
        }
        __syncthreads();
    }

#pragma unroll
    for (int r = 0; r < 8; r++) {
        int grow = row0 + ty * 8 + r;
        if (grow < n) {
            uint32 p[4];
#pragma unroll
            for (int c = 0; c < 4; c++)
                p[c] = (uint32)f2bf(acc[r][2 * c]) | ((uint32)f2bf(acc[r][2 * c + 1]) << 16);
            uint4 val = make_uint4(p[0], p[1], p[2], p[3]);
            *(uint4*)(C + (size_t)grow * M + tx * 8) = val;
        }
    }
}

// ---------- gather-aggregate, bf16 input, f32 output ----------
template<int M, bool RELU>
__launch_bounds__(256)
__global__ void gather_bf16(const ushort16* __restrict__ h,
                            const int* __restrict__ row_ptr,
                            const int* __restrict__ csr_src,
                            const float* __restrict__ dinv,
                            const float* __restrict__ bias,
                            float* __restrict__ outp, int n) {
    constexpr int LPG = M / 8;
    constexpr int GPB = 256 / LPG;
    const int g = threadIdx.x / LPG;
    const int l = threadIdx.x % LPG;
    const int v = blockIdx.x * GPB + g;
    if (v >= n) return;

    const float dv = dinv[v];
    float acc[8];

    {
        uint4 u = *(const uint4*)(h + (size_t)v * M + l * 8);
        float sn = dv * dv;
        acc[0] = bflo(u.x) * sn; acc[1] = bfhi(u.x) * sn;
        acc[2] = bflo(u.y) * sn; acc[3] = bfhi(u.y) * sn;
        acc[4] = bflo(u.z) * sn; acc[5] = bfhi(u.z) * sn;
        acc[6] = bflo(u.w) * sn; acc[7] = bfhi(u.w) * sn;
    }

    int j   = row_ptr[v];
    int end = row_ptr[v + 1];
    for (; j + 1 < end; j += 2) {
        int s0 = csr_src[j];
        int s1 = csr_src[j + 1];
        float n0 = dinv[s0] * dv;
        float n1 = dinv[s1] * dv;
        uint4 ua = *(const uint4*)(h + (size_t)s0 * M + l * 8);
        uint4 ub = *(const uint4*)(h + (size_t)s1 * M + l * 8);
        acc[0] += bflo(ua.x) * n0 + bflo(ub.x) * n1;
        acc[1] += bfhi(ua.x) * n0 + bfhi(ub.x) * n1;
        acc[2] += bflo(ua.y) * n0 + bflo(ub.y) * n1;
        acc[3] += bfhi(ua.y) * n0 + bfhi(ub.y) * n1;
        acc[4] += bflo(ua.z) * n0 + bflo(ub.z) * n1;
        acc[5] += bfhi(ua.z) * n0 + bfhi(ub.z) * n1;
        acc[6] += bflo(ua.w) * n0 + bflo(ub.w) * n1;
        acc[7] += bfhi(ua.w) * n0 + bfhi(ub.w) * n1;
    }
    if (j < end) {
        int s0 = csr_src[j];
        float n0 = dinv[s0] * dv;
        uint4 ua = *(const uint4*)(h + (size_t)s0 * M + l * 8);
        acc[0] += bflo(ua.x) * n0; acc[1] += bfhi(ua.x) * n0;
        acc[2] += bflo(ua.y) * n0; acc[3] += bfhi(ua.y) * n0;
        acc[4] += bflo(ua.z) * n0; acc[5] += bfhi(ua.z) * n0;
        acc[6] += bflo(ua.w) * n0; acc[7] += bfhi(ua.w) * n0;
    }

#pragma unroll
    for (int i = 0; i < 8; i++) {
        acc[i] += bias[l * 8 + i];
        if (RELU) acc[i] = fmaxf(acc[i], 0.0f);
    }
    float4 o0 = make_float4(acc[0], acc[1], acc[2], acc[3]);
    float4 o1 = make_float4(acc[4], acc[5], acc[6], acc[7]);
    float* op = outp + (size_t)v * M + l * 8;
    *(float4*)op = o0;
    *(float4*)(op + 4) = o1;
}

extern "C" void kernel_launch(void* const* d_in, const int* in_sizes, int n_in,
                              void* d_out, int out_size, void* d_ws, size_t ws_size,
                              hipStream_t stream) {
    const float* x  = (const float*)d_in[0];
    const float* W1 = (const float*)d_in[1];
    const float* b1 = (const float*)d_in[2];
    const float* W2 = (const float*)d_in[3];
    const float* b2 = (const float*)d_in[4];
    const int*   ei = (const int*)d_in[5];
    const int* src = ei;            // edge_index[0]
    const int* dst = ei + NEDGES;   // edge_index[1]
    float* out = (float*)d_out;

    // workspace layout (16B-aligned chunks):
    char* ws = (char*)d_ws;
    float* dinv     = (float*)ws;   ws += (size_t)NNODES * 4;
    int*   counts   = (int*)ws;     ws += (size_t)NNODES * 4;
    int*   row_ptr  = (int*)ws;     ws += (size_t)(NNODES + 4) * 4;
    int*   blk_sums = (int*)ws;     ws += 128 * 4;
    int*   blk_offs = (int*)ws;     ws += 128 * 4;
    int*   bcounts  = (int*)ws;     ws += 256 * 4;
    int*   boff     = (int*)ws;     ws += 260 * 4;
    int*   bcur     = (int*)ws;     ws += 256 * 4;
    int*   csr_src  = (int*)ws;     ws += (size_t)NEDGES * 4;
    uint2* staging  = (uint2*)ws;   ws += (size_t)NEDGES * 8;
    float* hr       = (float*)ws;   ws += (size_t)NNODES * HIDD * 4;
    ushort16* hbf   = (ushort16*)ws;

    // ---- CSR build via two-phase LDS binning ----
    hipMemsetAsync(bcounts, 0, NBUCK * 4, stream);
    k_hist<<<(NEDGES + HIST_EPB - 1) / HIST_EPB, 256, 0, stream>>>(dst, bcounts, NEDGES);
    k_bscan<<<1, 256, 0, stream>>>(bcounts, boff, bcur);
    k_bin<<<(NEDGES + BIN_EPB - 1) / BIN_EPB, 256, 0, stream>>>(src, dst, bcur, staging, NEDGES);
    k_ncount<<<NBUCK, 256, 0, stream>>>(staging, boff, counts, NNODES);
    finalize_dinv<<<(NNODES + 255) / 256, 256, 0, stream>>>(counts, dinv, NNODES);
    scan_phase_a<<<NSCAN, SCAN_BLK, 0, stream>>>(counts, row_ptr, blk_sums, NNODES);
    scan_phase_b<<<1, 128, 0, stream>>>(blk_sums, blk_offs, NSCAN);
    scan_phase_c<<<(NNODES + 255) / 256, 256, 0, stream>>>(row_ptr, blk_offs, NNODES);
    k_fill2<<<NBUCK, 256, 0, stream>>>(staging, boff, row_ptr, csr_src, NNODES);

    // ---- layer 1: h1(bf16) = x @ W1 ; hr = relu(Ahat @ h1 + b1) ----
    gemm_bf16out<IND, HIDD><<<(NNODES + 127) / 128, 256, 0, stream>>>(x, W1, hbf, NNODES);
    gather_bf16<HIDD, true><<<(NNODES * (HIDD / 8) + 255) / 256, 256, 0, stream>>>(
        hbf, row_ptr, csr_src, dinv, b1, hr, NNODES);

    // ---- layer 2: h2(bf16) = hr @ W2 ; out = Ahat @ h2 + b2 ----
    gemm_bf16out<HIDD, OUTD><<<(NNODES + 255) / 256, 256, 0, stream>>>(hr, W2, hbf, NNODES);
    gather_bf16<OUTD, false><<<(NNODES * (OUTD / 8) + 255) / 256, 256, 0, stream>>>(
        hbf, row_ptr, csr_src, dinv, b2, out, NNODES);
}

// Round 6
// 424.085 us; speedup vs baseline: 10.3433x; 1.0482x over previous
//
#include <hip/hip_runtime.h>

#define NNODES 100000
#define NEDGES 1600000
#define IND 128
#define HIDD 128
#define OUTD 64

// bucketed CSR build
#define BSHIFT 9
#define BSIZE  512
#define NBUCK  ((NNODES + BSIZE - 1) / BSIZE)        // 196
#define HIST_EPB 8192
#define BIN_EPB  4096
#define SEG_CAP  10240

typedef unsigned int  uint32;
typedef unsigned short ushort16;

// ---------- bf16 helpers ----------
__device__ __forceinline__ unsigned short f2bf(float f) {
    union { float f; uint32 u; } x; x.f = f;
    uint32 u = x.u;
    return (unsigned short)((u + 0x7fffu + ((u >> 16) & 1u)) >> 16);   // RNE
}
__device__ __forceinline__ float bflo(uint32 u) {
    union { uint32 i; float f; } x; x.i = u << 16; return x.f;
}
__device__ __forceinline__ float bfhi(uint32 u) {
    union { uint32 i; float f; } x; x.i = u & 0xffff0000u; return x.f;
}

// ---------- phase A: bucket histogram (LDS-aggregated) ----------
__global__ void k_hist(const int* __restrict__ dst, int* __restrict__ bcounts, int e) {
    __shared__ int lh[NBUCK];
    for (int i = threadIdx.x; i < NBUCK; i += 256) lh[i] = 0;
    __syncthreads();
    int start = blockIdx.x * HIST_EPB;
    int end = min(start + HIST_EPB, e);
    for (int i = start + threadIdx.x; i < end; i += 256)
        atomicAdd(&lh[dst[i] >> BSHIFT], 1);
    __syncthreads();
    for (int i = threadIdx.x; i < NBUCK; i += 256)
        if (lh[i]) atomicAdd(&bcounts[i], lh[i]);
}

// ---------- phase B: scan bucket counts (1 block) ----------
__global__ void k_bscan(const int* __restrict__ bcounts, int* __restrict__ boff,
                        int* __restrict__ bcur) {
    __shared__ int buf[256];
    const int tid = threadIdx.x;
    int v = (tid < NBUCK) ? bcounts[tid] : 0;
    buf[tid] = v;
    __syncthreads();
    for (int off = 1; off < 256; off <<= 1) {
        int t = (tid >= off) ? buf[tid - off] : 0;
        __syncthreads();
        buf[tid] += t;
        __syncthreads();
    }
    if (tid < NBUCK) { int ex = buf[tid] - v; boff[tid] = ex; bcur[tid] = ex; }
    if (tid == 255) boff[NBUCK] = buf[255];
}

// ---------- phase C: bin (src,dst) pairs into bucket-contiguous packed staging ----------
// staging entry: (dst_local << 17) | src   (src < 2^17, dst_local < 512)
__global__ void k_bin(const int* __restrict__ src, const int* __restrict__ dst,
                      int* __restrict__ bcur, uint32* __restrict__ staging, int e) {
    __shared__ int lh[NBUCK];
    __shared__ int lbase[NBUCK];
    __shared__ int lcur[NBUCK];
    __shared__ int gbase[NBUCK];
    __shared__ int sbuf[256];
    __shared__ uint2 lp[BIN_EPB];  // 32 KB

    const int tid = threadIdx.x;
    for (int i = tid; i < NBUCK; i += 256) lh[i] = 0;
    __syncthreads();

    int start = blockIdx.x * BIN_EPB;
    int end = min(start + BIN_EPB, e);
    int n = end - start;

    for (int i = start + tid; i < end; i += 256)
        atomicAdd(&lh[dst[i] >> BSHIFT], 1);
    __syncthreads();

    int v = (tid < NBUCK) ? lh[tid] : 0;
    sbuf[tid] = v;
    __syncthreads();
    for (int off = 1; off < 256; off <<= 1) {
        int t = (tid >= off) ? sbuf[tid - off] : 0;
        __syncthreads();
        sbuf[tid] += t;
        __syncthreads();
    }
    if (tid < NBUCK) { int ex = sbuf[tid] - v; lbase[tid] = ex; lcur[tid] = ex; }
    __syncthreads();

    for (int i = start + tid; i < end; i += 256) {
        int d = dst[i], s = src[i];
        int b = d >> BSHIFT;
        int pos = atomicAdd(&lcur[b], 1);
        lp[pos] = make_uint2((uint32)s, (uint32)d);
    }
    if (tid < NBUCK) {
        int c = lh[tid];
        gbase[tid] = c ? atomicAdd(&bcur[tid], c) : 0;
    }
    __syncthreads();

    for (int i = tid; i < n; i += 256) {
        uint2 p = lp[i];
        int b = (int)(p.y >> BSHIFT);
        uint32 packed = ((p.y & (BSIZE - 1)) << 17) | p.x;
        staging[gbase[b] + (i - lbase[b])] = packed;
    }
}

// ---------- phase D (fused): per-bucket counts + dinv + row_ptr + counting-sort csr ----------
__global__ void k_fill3(const uint32* __restrict__ staging, const int* __restrict__ boff,
                        int* __restrict__ row_ptr, int* __restrict__ csr_src,
                        float* __restrict__ dinv, int n) {
    __shared__ int nc[BSIZE];       // per-node in-degree
    __shared__ int lcur[BSIZE];     // scatter cursor (starts at local excl scan)
    __shared__ int sbuf[256];
    __shared__ int seg[SEG_CAP];    // 40 KB sorted segment
    const int b = blockIdx.x;
    const int base = b << BSHIFT;
    const int tid = threadIdx.x;
    const int nn = min(BSIZE, n - base);

    for (int i = tid; i < BSIZE; i += 256) nc[i] = 0;
    __syncthreads();

    const int s0 = boff[b], s1 = boff[b + 1];
    for (int i = s0 + tid; i < s1; i += 256)
        atomicAdd(&nc[staging[i] >> 17], 1);
    __syncthreads();

    // exclusive scan of nc[0..511]: thread t owns elements 2t, 2t+1
    int a0 = nc[2 * tid], a1 = nc[2 * tid + 1];
    sbuf[tid] = a0 + a1;
    __syncthreads();
    for (int off = 1; off < 256; off <<= 1) {
        int t = (tid >= off) ? sbuf[tid - off] : 0;
        __syncthreads();
        sbuf[tid] += t;
        __syncthreads();
    }
    int ex = sbuf[tid] - (a0 + a1);           // exclusive at position 2t
    const int r0 = s0;                         // bucket's edge base == row_ptr[base]
    if (2 * tid < nn) {
        row_ptr[base + 2 * tid] = r0 + ex;
        dinv[base + 2 * tid] = rsqrtf((float)(a0 + 1));
    }
    if (2 * tid + 1 < nn) {
        row_ptr[base + 2 * tid + 1] = r0 + ex + a0;
        dinv[base + 2 * tid + 1] = rsqrtf((float)(a1 + 1));
    }
    lcur[2 * tid] = ex;
    lcur[2 * tid + 1] = ex + a0;
    if (b == (int)gridDim.x - 1 && tid == 255) row_ptr[n] = s1;   // = NEDGES
    __syncthreads();

    const int L = s1 - s0;
    for (int i = s0 + tid; i < s1; i += 256) {
        uint32 p = staging[i];
        int dl = (int)(p >> 17);
        int s  = (int)(p & 0x1FFFFu);
        int pos = atomicAdd(&lcur[dl], 1);
        if (pos < SEG_CAP) seg[pos] = s;
        else               csr_src[r0 + pos] = s;    // overflow fallback
    }
    __syncthreads();
    int lim = min(L, SEG_CAP);
    for (int i = tid; i < lim; i += 256) csr_src[r0 + i] = seg[i];
}

// ---------- register-tiled fp32 GEMM, bf16 output premultiplied by dinv[row] ----------
template<int K, int M>
__global__ void gemm_bf16out(const float* __restrict__ A, const float* __restrict__ W,
                             const float* __restrict__ dinv,
                             ushort16* __restrict__ C, int n) {
    constexpr int CG = M / 8;
    constexpr int BR = (256 / CG) * 8;
    __shared__ float As[BR * 32];
    __shared__ float Ws[32 * M];

    const int tx = threadIdx.x % CG;
    const int ty = threadIdx.x / CG;
    const int row0 = blockIdx.x * BR;

    float acc[8][8];
#pragma unroll
    for (int r = 0; r < 8; r++)
#pragma unroll
        for (int c = 0; c < 8; c++) acc[r][c] = 0.0f;

    float4* Asf4 = (float4*)As;
    float4* Wsf4 = (float4*)Ws;

    for (int kc = 0; kc < K; kc += 32) {
#pragma unroll
        for (int i = 0; i < BR / 32; i++) {
            int idx = threadIdx.x + i * 256;
            int row = idx >> 3, kq = idx & 7;
            int grow = row0 + row;
            if (grow >= n) grow = n - 1;
            Asf4[idx] = *(const float4*)(A + (size_t)grow * K + kc + kq * 4);
        }
#pragma unroll
        for (int i = 0; i < (32 * M / 4) / 256; i++) {
            int idx = threadIdx.x + i * 256;
            Wsf4[idx] = ((const float4*)(W + (size_t)kc * M))[idx];
        }
        __syncthreads();

#pragma unroll
        for (int kk0 = 0; kk0 < 32; kk0 += 4) {
            float4 a[8];
#pragma unroll
            for (int r = 0; r < 8; r++)
                a[r] = Asf4[(ty * 8 + r) * 8 + (kk0 >> 2)];
#pragma unroll
            for (int j = 0; j < 4; j++) {
                int base = (kk0 + j) * (M / 4) + tx * 2;
                float4 w0 = Wsf4[base];
                float4 w1 = Wsf4[base + 1];
#pragma unroll
                for (int r = 0; r < 8; r++) {
                    float av = (j == 0) ? a[r].x : (j == 1) ? a[r].y : (j == 2) ? a[r].z : a[r].w;
                    acc[r][0] += av * w0.x; acc[r][1] += av * w0.y;
                    acc[r][2] += av * w0.z; acc[r][3] += av * w0.w;
                    acc[r][4] += av * w1.x; acc[r][5] += av * w1.y;
                    acc[r][6] += av * w1.z; acc[r][7] += av * w1.w;
                }
            }
        }
        __syncthreads();
    }

#pragma unroll
    for (int r = 0; r < 8; r++) {
        int grow = row0 + ty * 8 + r;
        if (grow < n) {
            float dv = dinv[grow];
            uint32 p[4];
#pragma unroll
            for (int c = 0; c < 4; c++)
                p[c] = (uint32)f2bf(acc[r][2 * c] * dv) |
                       ((uint32)f2bf(acc[r][2 * c + 1] * dv) << 16);
            uint4 val = make_uint4(p[0], p[1], p[2], p[3]);
            *(uint4*)(C + (size_t)grow * M + tx * 8) = val;
        }
    }
}

// ---------- gather-aggregate over premultiplied bf16 table ----------
// out[v] = [relu]( (sum_{s in N(v)} hpre[s] + hpre[v]) * dinv[v] + bias )
template<int M, bool RELU>
__launch_bounds__(256)
__global__ void gather_bf16(const ushort16* __restrict__ h,
                            const int* __restrict__ row_ptr,
                            const int* __restrict__ csr_src,
                            const float* __restrict__ dinv,
                            const float* __restrict__ bias,
                            float* __restrict__ outp, int n) {
    constexpr int LPG = M / 8;
    constexpr int GPB = 256 / LPG;
    const int g = threadIdx.x / LPG;
    const int l = threadIdx.x % LPG;
    const int v = blockIdx.x * GPB + g;
    if (v >= n) return;

    const float dv = dinv[v];
    float acc[8];

    // self term (premultiplied): hpre[v]
    {
        uint4 u = *(const uint4*)(h + (size_t)v * M + l * 8);
        acc[0] = bflo(u.x); acc[1] = bfhi(u.x);
        acc[2] = bflo(u.y); acc[3] = bfhi(u.y);
        acc[4] = bflo(u.z); acc[5] = bfhi(u.z);
        acc[6] = bflo(u.w); acc[7] = bfhi(u.w);
    }

    int j   = row_ptr[v];
    int end = row_ptr[v + 1];
    for (; j + 3 < end; j += 4) {
        int s0 = csr_src[j];
        int s1 = csr_src[j + 1];
        int s2 = csr_src[j + 2];
        int s3 = csr_src[j + 3];
        uint4 u0 = *(const uint4*)(h + (size_t)s0 * M + l * 8);
        uint4 u1 = *(const uint4*)(h + (size_t)s1 * M + l * 8);
        uint4 u2 = *(const uint4*)(h + (size_t)s2 * M + l * 8);
        uint4 u3 = *(const uint4*)(h + (size_t)s3 * M + l * 8);
        acc[0] += (bflo(u0.x) + bflo(u1.x)) + (bflo(u2.x) + bflo(u3.x));
        acc[1] += (bfhi(u0.x) + bfhi(u1.x)) + (bfhi(u2.x) + bfhi(u3.x));
        acc[2] += (bflo(u0.y) + bflo(u1.y)) + (bflo(u2.y) + bflo(u3.y));
        acc[3] += (bfhi(u0.y) + bfhi(u1.y)) + (bfhi(u2.y) + bfhi(u3.y));
        acc[4] += (bflo(u0.z) + bflo(u1.z)) + (bflo(u2.z) + bflo(u3.z));
        acc[5] += (bfhi(u0.z) + bfhi(u1.z)) + (bfhi(u2.z) + bfhi(u3.z));
        acc[6] += (bflo(u0.w) + bflo(u1.w)) + (bflo(u2.w) + bflo(u3.w));
        acc[7] += (bfhi(u0.w) + bfhi(u1.w)) + (bfhi(u2.w) + bfhi(u3.w));
    }
    for (; j < end; j++) {
        int s0 = csr_src[j];
        uint4 u0 = *(const uint4*)(h + (size_t)s0 * M + l * 8);
        acc[0] += bflo(u0.x); acc[1] += bfhi(u0.x);
        acc[2] += bflo(u0.y); acc[3] += bfhi(u0.y);
        acc[4] += bflo(u0.z); acc[5] += bfhi(u0.z);
        acc[6] += bflo(u0.w); acc[7] += bfhi(u0.w);
    }

#pragma unroll
    for (int i = 0; i < 8; i++) {
        acc[i] = acc[i] * dv + bias[l * 8 + i];
        if (RELU) acc[i] = fmaxf(acc[i], 0.0f);
    }
    float4 o0 = make_float4(acc[0], acc[1], acc[2], acc[3]);
    float4 o1 = make_float4(acc[4], acc[5], acc[6], acc[7]);
    float* op = outp + (size_t)v * M + l * 8;
    *(float4*)op = o0;
    *(float4*)(op + 4) = o1;
}

extern "C" void kernel_launch(void* const* d_in, const int* in_sizes, int n_in,
                              void* d_out, int out_size, void* d_ws, size_t ws_size,
                              hipStream_t stream) {
    const float* x  = (const float*)d_in[0];
    const float* W1 = (const float*)d_in[1];
    const float* b1 = (const float*)d_in[2];
    const float* W2 = (const float*)d_in[3];
    const float* b2 = (const float*)d_in[4];
    const int*   ei = (const int*)d_in[5];
    const int* src = ei;            // edge_index[0]
    const int* dst = ei + NEDGES;   // edge_index[1]
    float* out = (float*)d_out;

    // workspace layout (16B-aligned chunks):
    char* ws = (char*)d_ws;
    float*  dinv    = (float*)ws;   ws += (size_t)NNODES * 4;
    int*    row_ptr = (int*)ws;     ws += (size_t)(NNODES + 4) * 4;
    int*    bcounts = (int*)ws;     ws += 256 * 4;
    int*    boff    = (int*)ws;     ws += 260 * 4;
    int*    bcur    = (int*)ws;     ws += 256 * 4;
    int*    csr_src = (int*)ws;     ws += (size_t)NEDGES * 4;
    uint32* staging = (uint32*)ws;  ws += (size_t)NEDGES * 4;
    float*  hr      = (float*)ws;   ws += (size_t)NNODES * HIDD * 4;
    ushort16* hbf   = (ushort16*)ws;

    // ---- CSR build ----
    hipMemsetAsync(bcounts, 0, NBUCK * 4, stream);
    k_hist<<<(NEDGES + HIST_EPB - 1) / HIST_EPB, 256, 0, stream>>>(dst, bcounts, NEDGES);
    k_bscan<<<1, 256, 0, stream>>>(bcounts, boff, bcur);
    k_bin<<<(NEDGES + BIN_EPB - 1) / BIN_EPB, 256, 0, stream>>>(src, dst, bcur, staging, NEDGES);
    k_fill3<<<NBUCK, 256, 0, stream>>>(staging, boff, row_ptr, csr_src, dinv, NNODES);

    // ---- layer 1: hpre1(bf16) = (x @ W1) * dinv ; hr = relu(gather + b1) ----
    gemm_bf16out<IND, HIDD><<<(NNODES + 127) / 128, 256, 0, stream>>>(x, W1, dinv, hbf, NNODES);
    gather_bf16<HIDD, true><<<(NNODES * (HIDD / 8) + 255) / 256, 256, 0, stream>>>(
        hbf, row_ptr, csr_src, dinv, b1, hr, NNODES);

    // ---- layer 2: hpre2(bf16) = (hr @ W2) * dinv ; out = gather + b2 ----
    gemm_bf16out<HIDD, OUTD><<<(NNODES + 255) / 256, 256, 0, stream>>>(hr, W2, dinv, hbf, NNODES);
    gather_bf16<OUTD, false><<<(NNODES * (OUTD / 8) + 255) / 256, 256, 0, stream>>>(
        hbf, row_ptr, csr_src, dinv, b2, out, NNODES);
}

// Round 7
// 330.990 us; speedup vs baseline: 13.2525x; 1.2813x over previous
//
#include <hip/hip_runtime.h>

#define NNODES 100000
#define NEDGES 1600000
#define IND 128
#define HIDD 128
#define OUTD 64

// bucketed CSR build
#define BSHIFT 9
#define BSIZE  512
#define NBUCK  ((NNODES + BSIZE - 1) / BSIZE)        // 196
#define HIST_EPB 8192
#define BIN_EPB  4096
#define SEG_CAP  10240

typedef unsigned int  uint32;
typedef unsigned short ushort16;
typedef __attribute__((ext_vector_type(8))) short short8;
typedef __attribute__((ext_vector_type(4))) float floatx4;

// ---------- bf16 helpers ----------
__device__ __forceinline__ unsigned short f2bf(float f) {
    union { float f; uint32 u; } x; x.f = f;
    uint32 u = x.u;
    return (unsigned short)((u + 0x7fffu + ((u >> 16) & 1u)) >> 16);   // RNE
}
__device__ __forceinline__ float bflo(uint32 u) {
    union { uint32 i; float f; } x; x.i = u << 16; return x.f;
}
__device__ __forceinline__ float bfhi(uint32 u) {
    union { uint32 i; float f; } x; x.i = u & 0xffff0000u; return x.f;
}

// ---------- phase A: bucket histogram (LDS-aggregated) ----------
__global__ void k_hist(const int* __restrict__ dst, int* __restrict__ bcounts, int e) {
    __shared__ int lh[NBUCK];
    for (int i = threadIdx.x; i < NBUCK; i += 256) lh[i] = 0;
    __syncthreads();
    int start = blockIdx.x * HIST_EPB;
    int end = min(start + HIST_EPB, e);
    for (int i = start + threadIdx.x; i < end; i += 256)
        atomicAdd(&lh[dst[i] >> BSHIFT], 1);
    __syncthreads();
    for (int i = threadIdx.x; i < NBUCK; i += 256)
        if (lh[i]) atomicAdd(&bcounts[i], lh[i]);
}

// ---------- phase B: scan bucket counts (1 block) ----------
__global__ void k_bscan(const int* __restrict__ bcounts, int* __restrict__ boff,
                        int* __restrict__ bcur) {
    __shared__ int buf[256];
    const int tid = threadIdx.x;
    int v = (tid < NBUCK) ? bcounts[tid] : 0;
    buf[tid] = v;
    __syncthreads();
    for (int off = 1; off < 256; off <<= 1) {
        int t = (tid >= off) ? buf[tid - off] : 0;
        __syncthreads();
        buf[tid] += t;
        __syncthreads();
    }
    if (tid < NBUCK) { int ex = buf[tid] - v; boff[tid] = ex; bcur[tid] = ex; }
    if (tid == 255) boff[NBUCK] = buf[255];
}

// ---------- phase C: bin (src,dst) into bucket-contiguous packed staging ----------
// staging entry: (dst_local << 17) | src
__global__ void k_bin(const int* __restrict__ src, const int* __restrict__ dst,
                      int* __restrict__ bcur, uint32* __restrict__ staging, int e) {
    __shared__ int lh[NBUCK];
    __shared__ int lbase[NBUCK];
    __shared__ int lcur[NBUCK];
    __shared__ int gbase[NBUCK];
    __shared__ int sbuf[256];
    __shared__ uint2 lp[BIN_EPB];  // 32 KB

    const int tid = threadIdx.x;
    for (int i = tid; i < NBUCK; i += 256) lh[i] = 0;
    __syncthreads();

    int start = blockIdx.x * BIN_EPB;
    int end = min(start + BIN_EPB, e);
    int n = end - start;

    for (int i = start + tid; i < end; i += 256)
        atomicAdd(&lh[dst[i] >> BSHIFT], 1);
    __syncthreads();

    int v = (tid < NBUCK) ? lh[tid] : 0;
    sbuf[tid] = v;
    __syncthreads();
    for (int off = 1; off < 256; off <<= 1) {
        int t = (tid >= off) ? sbuf[tid - off] : 0;
        __syncthreads();
        sbuf[tid] += t;
        __syncthreads();
    }
    if (tid < NBUCK) { int ex = sbuf[tid] - v; lbase[tid] = ex; lcur[tid] = ex; }
    __syncthreads();

    for (int i = start + tid; i < end; i += 256) {
        int d = dst[i], s = src[i];
        int b = d >> BSHIFT;
        int pos = atomicAdd(&lcur[b], 1);
        lp[pos] = make_uint2((uint32)s, (uint32)d);
    }
    if (tid < NBUCK) {
        int c = lh[tid];
        gbase[tid] = c ? atomicAdd(&bcur[tid], c) : 0;
    }
    __syncthreads();

    for (int i = tid; i < n; i += 256) {
        uint2 p = lp[i];
        int b = (int)(p.y >> BSHIFT);
        uint32 packed = ((p.y & (BSIZE - 1)) << 17) | p.x;
        staging[gbase[b] + (i - lbase[b])] = packed;
    }
}

// ---------- phase D (fused): per-bucket counts + dinv + row_ptr + counting-sort csr ----------
__global__ void k_fill3(const uint32* __restrict__ staging, const int* __restrict__ boff,
                        int* __restrict__ row_ptr, int* __restrict__ csr_src,
                        float* __restrict__ dinv, int n) {
    __shared__ int nc[BSIZE];
    __shared__ int lcur[BSIZE];
    __shared__ int sbuf[256];
    __shared__ int seg[SEG_CAP];    // 40 KB
    const int b = blockIdx.x;
    const int base = b << BSHIFT;
    const int tid = threadIdx.x;
    const int nn = min(BSIZE, n - base);

    for (int i = tid; i < BSIZE; i += 256) nc[i] = 0;
    __syncthreads();

    const int s0 = boff[b], s1 = boff[b + 1];
    for (int i = s0 + tid; i < s1; i += 256)
        atomicAdd(&nc[staging[i] >> 17], 1);
    __syncthreads();

    int a0 = nc[2 * tid], a1 = nc[2 * tid + 1];
    sbuf[tid] = a0 + a1;
    __syncthreads();
    for (int off = 1; off < 256; off <<= 1) {
        int t = (tid >= off) ? sbuf[tid - off] : 0;
        __syncthreads();
        sbuf[tid] += t;
        __syncthreads();
    }
    int ex = sbuf[tid] - (a0 + a1);
    const int r0 = s0;
    if (2 * tid < nn) {
        row_ptr[base + 2 * tid] = r0 + ex;
        dinv[base + 2 * tid] = rsqrtf((float)(a0 + 1));
    }
    if (2 * tid + 1 < nn) {
        row_ptr[base + 2 * tid + 1] = r0 + ex + a0;
        dinv[base + 2 * tid + 1] = rsqrtf((float)(a1 + 1));
    }
    lcur[2 * tid] = ex;
    lcur[2 * tid + 1] = ex + a0;
    if (b == (int)gridDim.x - 1 && tid == 255) row_ptr[n] = s1;
    __syncthreads();

    const int L = s1 - s0;
    for (int i = s0 + tid; i < s1; i += 256) {
        uint32 p = staging[i];
        int dl = (int)(p >> 17);
        int s  = (int)(p & 0x1FFFFu);
        int pos = atomicAdd(&lcur[dl], 1);
        if (pos < SEG_CAP) seg[pos] = s;
        else               csr_src[r0 + pos] = s;
    }
    __syncthreads();
    int lim = min(L, SEG_CAP);
    for (int i = tid; i < lim; i += 256) csr_src[r0 + i] = seg[i];
}

// ---------- W transpose + bf16 convert: WT[m][k] = bf16(W[k][m]) ----------
template<int K, int M>
__global__ void k_wt(const float* __restrict__ W, unsigned short* __restrict__ WT) {
    int idx = blockIdx.x * 256 + threadIdx.x;
    if (idx < K * M) {
        int k = idx / M, m = idx - k * M;
        WT[m * K + k] = f2bf(W[idx]);
    }
}

// ---------- MFMA bf16 GEMM: C[n x M](bf16, premult by dinv) = A[n x K](f32) @ W ----------
// WT = bf16 W transposed [M][K]. Block: 256 thr / 4 waves, 64 rows; K fully staged.
template<int K, int M>
__launch_bounds__(256)
__global__ void gemm_mfma(const float* __restrict__ A, const unsigned short* __restrict__ WT,
                          const float* __restrict__ dinv, unsigned short* __restrict__ C, int n) {
    constexpr int KP = K + 8;            // padded bf16 row stride (272 B, 16B-aligned)
    constexpr int NT = M / 16;           // column tiles
    __shared__ unsigned short Asl[64 * KP];
    __shared__ unsigned short Wsl[M * KP];

    const int tid = threadIdx.x;
    const int row0 = blockIdx.x * 64;

    // stage WT rows (bf16, contiguous) -> padded LDS rows
    {
        constexpr int SEG = (K * 2) / 16;             // uint4 per row
        const uint4* srcp = (const uint4*)WT;
        for (int idx = tid; idx < M * SEG; idx += 256) {
            int r = idx / SEG, s = idx - r * SEG;
            *(uint4*)(Wsl + r * KP + s * 8) = srcp[idx];
        }
    }
    // stage A rows: fp32 global -> bf16 LDS
    {
        constexpr int F4R = K / 4;                    // float4 per row
        for (int idx = tid; idx < 64 * F4R; idx += 256) {
            int r = idx / F4R, s = idx - r * F4R;
            int grow = row0 + r; if (grow >= n) grow = n - 1;
            float4 v = *(const float4*)(A + (size_t)grow * K + s * 4);
            uint32 p0 = (uint32)f2bf(v.x) | ((uint32)f2bf(v.y) << 16);
            uint32 p1 = (uint32)f2bf(v.z) | ((uint32)f2bf(v.w) << 16);
            *(uint2*)(Asl + r * KP + s * 4) = make_uint2(p0, p1);
        }
    }
    __syncthreads();

    const int lane = tid & 63;
    const int wave = tid >> 6;
    const int mm = lane & 15;            // A row / B col within tile
    const int qq = lane >> 4;            // k-quad

    floatx4 acc[NT];
#pragma unroll
    for (int t = 0; t < NT; t++) acc[t] = (floatx4){0.f, 0.f, 0.f, 0.f};

#pragma unroll
    for (int kc = 0; kc < K / 32; kc++) {
        short8 a = *(const short8*)(Asl + (wave * 16 + mm) * KP + kc * 32 + qq * 8);
#pragma unroll
        for (int t = 0; t < NT; t++) {
            short8 b = *(const short8*)(Wsl + (t * 16 + mm) * KP + kc * 32 + qq * 8);
            acc[t] = __builtin_amdgcn_mfma_f32_16x16x32_bf16(a, b, acc[t], 0, 0, 0);
        }
    }

    // epilogue: lane holds C[row0 + wave*16 + qq*4 + r][t*16 + mm]
#pragma unroll
    for (int r = 0; r < 4; r++) {
        int grow = row0 + wave * 16 + qq * 4 + r;
        if (grow < n) {
            float dv = dinv[grow];
#pragma unroll
            for (int t = 0; t < NT; t++)
                C[(size_t)grow * M + t * 16 + mm] = f2bf(acc[t][r] * dv);
        }
    }
}

// ---------- gather-aggregate over premultiplied bf16 table ----------
template<int M, bool RELU>
__launch_bounds__(256)
__global__ void gather_bf16(const ushort16* __restrict__ h,
                            const int* __restrict__ row_ptr,
                            const int* __restrict__ csr_src,
                            const float* __restrict__ dinv,
                            const float* __restrict__ bias,
                            float* __restrict__ outp, int n) {
    constexpr int LPG = M / 8;
    constexpr int GPB = 256 / LPG;
    const int g = threadIdx.x / LPG;
    const int l = threadIdx.x % LPG;
    const int v = blockIdx.x * GPB + g;
    if (v >= n) return;

    const float dv = dinv[v];
    float acc[8];

    {
        uint4 u = *(const uint4*)(h + (size_t)v * M + l * 8);
        acc[0] = bflo(u.x); acc[1] = bfhi(u.x);
        acc[2] = bflo(u.y); acc[3] = bfhi(u.y);
        acc[4] = bflo(u.z); acc[5] = bfhi(u.z);
        acc[6] = bflo(u.w); acc[7] = bfhi(u.w);
    }

    int j   = row_ptr[v];
    int end = row_ptr[v + 1];
    for (; j + 3 < end; j += 4) {
        int s0 = csr_src[j];
        int s1 = csr_src[j + 1];
        int s2 = csr_src[j + 2];
        int s3 = csr_src[j + 3];
        uint4 u0 = *(const uint4*)(h + (size_t)s0 * M + l * 8);
        uint4 u1 = *(const uint4*)(h + (size_t)s1 * M + l * 8);
        uint4 u2 = *(const uint4*)(h + (size_t)s2 * M + l * 8);
        uint4 u3 = *(const uint4*)(h + (size_t)s3 * M + l * 8);
        acc[0] += (bflo(u0.x) + bflo(u1.x)) + (bflo(u2.x) + bflo(u3.x));
        acc[1] += (bfhi(u0.x) + bfhi(u1.x)) + (bfhi(u2.x) + bfhi(u3.x));
        acc[2] += (bflo(u0.y) + bflo(u1.y)) + (bflo(u2.y) + bflo(u3.y));
        acc[3] += (bfhi(u0.y) + bfhi(u1.y)) + (bfhi(u2.y) + bfhi(u3.y));
        acc[4] += (bflo(u0.z) + bflo(u1.z)) + (bflo(u2.z) + bflo(u3.z));
        acc[5] += (bfhi(u0.z) + bfhi(u1.z)) + (bfhi(u2.z) + bfhi(u3.z));
        acc[6] += (bflo(u0.w) + bflo(u1.w)) + (bflo(u2.w) + bflo(u3.w));
        acc[7] += (bfhi(u0.w) + bfhi(u1.w)) + (bfhi(u2.w) + bfhi(u3.w));
    }
    for (; j < end; j++) {
        int s0 = csr_src[j];
        uint4 u0 = *(const uint4*)(h + (size_t)s0 * M + l * 8);
        acc[0] += bflo(u0.x); acc[1] += bfhi(u0.x);
        acc[2] += bflo(u0.y); acc[3] += bfhi(u0.y);
        acc[4] += bflo(u0.z); acc[5] += bfhi(u0.z);
        acc[6] += bflo(u0.w); acc[7] += bfhi(u0.w);
    }

#pragma unroll
    for (int i = 0; i < 8; i++) {
        acc[i] = acc[i] * dv + bias[l * 8 + i];
        if (RELU) acc[i] = fmaxf(acc[i], 0.0f);
    }
    float4 o0 = make_float4(acc[0], acc[1], acc[2], acc[3]);
    float4 o1 = make_float4(acc[4], acc[5], acc[6], acc[7]);
    float* op = outp + (size_t)v * M + l * 8;
    *(float4*)op = o0;
    *(float4*)(op + 4) = o1;
}

extern "C" void kernel_launch(void* const* d_in, const int* in_sizes, int n_in,
                              void* d_out, int out_size, void* d_ws, size_t ws_size,
                              hipStream_t stream) {
    const float* x  = (const float*)d_in[0];
    const float* W1 = (const float*)d_in[1];
    const float* b1 = (const float*)d_in[2];
    const float* W2 = (const float*)d_in[3];
    const float* b2 = (const float*)d_in[4];
    const int*   ei = (const int*)d_in[5];
    const int* src = ei;            // edge_index[0]
    const int* dst = ei + NEDGES;   // edge_index[1]
    float* out = (float*)d_out;

    // workspace layout (16B-aligned chunks):
    char* ws = (char*)d_ws;
    float*  dinv    = (float*)ws;   ws += (size_t)NNODES * 4;
    int*    row_ptr = (int*)ws;     ws += (size_t)(NNODES + 4) * 4;
    int*    bcounts = (int*)ws;     ws += 256 * 4;
    int*    boff    = (int*)ws;     ws += 260 * 4;
    int*    bcur    = (int*)ws;     ws += 256 * 4;
    unsigned short* wt1 = (unsigned short*)ws;  ws += (size_t)IND * HIDD * 2;
    unsigned short* wt2 = (unsigned short*)ws;  ws += (size_t)HIDD * OUTD * 2;
    int*    csr_src = (int*)ws;     ws += (size_t)NEDGES * 4;
    uint32* staging = (uint32*)ws;  ws += (size_t)NEDGES * 4;
    float*  hr      = (float*)ws;   ws += (size_t)NNODES * HIDD * 4;
    ushort16* hbf   = (ushort16*)ws;

    // ---- CSR build ----
    hipMemsetAsync(bcounts, 0, NBUCK * 4, stream);
    k_hist<<<(NEDGES + HIST_EPB - 1) / HIST_EPB, 256, 0, stream>>>(dst, bcounts, NEDGES);
    k_bscan<<<1, 256, 0, stream>>>(bcounts, boff, bcur);
    k_bin<<<(NEDGES + BIN_EPB - 1) / BIN_EPB, 256, 0, stream>>>(src, dst, bcur, staging, NEDGES);
    k_fill3<<<NBUCK, 256, 0, stream>>>(staging, boff, row_ptr, csr_src, dinv, NNODES);

    // ---- weight transposes (bf16) ----
    k_wt<IND, HIDD><<<(IND * HIDD + 255) / 256, 256, 0, stream>>>(W1, wt1);
    k_wt<HIDD, OUTD><<<(HIDD * OUTD + 255) / 256, 256, 0, stream>>>(W2, wt2);

    // ---- layer 1: hpre1(bf16) = (x @ W1) * dinv ; hr = relu(gather * dv + b1) ----
    gemm_mfma<IND, HIDD><<<(NNODES + 63) / 64, 256, 0, stream>>>(
        x, wt1, dinv, (unsigned short*)hbf, NNODES);
    gather_bf16<HIDD, true><<<(NNODES * (HIDD / 8) + 255) / 256, 256, 0, stream>>>(
        hbf, row_ptr, csr_src, dinv, b1, hr, NNODES);

    // ---- layer 2: hpre2(bf16) = (hr @ W2) * dinv ; out = gather * dv + b2 ----
    gemm_mfma<HIDD, OUTD><<<(NNODES + 63) / 64, 256, 0, stream>>>(
        hr, wt2, dinv, (unsigned short*)hbf, NNODES);
    gather_bf16<OUTD, false><<<(NNODES * (OUTD / 8) + 255) / 256, 256, 0, stream>>>(
        hbf, row_ptr, csr_src, dinv, b2, out, NNODES);
}